// Round 6
// baseline (171.790 us; speedup 1.0000x reference)
//
#include <hip/hip_runtime.h>
#include <math.h>

#define BTOT 131072
#define NBK 3
#define SS 16
#define NA 9
#define BAD 25      // SS+NA
#define STR 28      // padded row stride in the fp32 weight image
#define VD 128
#define CM 10
#define OUTD 51     // NBK*SS + 3
#define EPS 1e-8f

// ---- fp32 folded-weight image (float offsets in ws) ----
#define O_GQK  0        // 25 x 28  full Wq^T Wk
#define O_GQQ  700      // 25 x 28  lower-tri (off-diag x2) of Wq^T Wq
#define O_GKK  1400     // 25 x 28  lower-tri (off-diag x2) of Wk^T Wk
#define O_V1   2100     // 28: Wq^T bk
#define O_V2   2128     // 28: Wk^T bq
#define O_VQ   2156     // 28: Wq^T bq
#define O_VK   2184     // 28: Wk^T bk
#define O_C    2212     // c0, cq, ck, pad
#define O_M    2216     // (dead region)
#define O_B2   7976     // 16
#define O_WC1  7992     // 10 x 84
#define O_BC1  8832     // 12
#define O_WC2  8844     // 3 x 12
#define O_BC2  8880     // 4
#define LDS_F  8884
// ---- bf16 MFMA-packed B-fragments appended after the fp32 image ----
#define O_PKM  LDS_F          // 4096 ushorts = 2048 floats
#define O_PKW2 (LDS_F + 2048) // 2048 ushorts = 1024 floats
#define PKM_N  4096
#define PKW2_N 2048

#define NDOT  (O_M + PKM_N)   // 2216 fp32 dots + 4096 pkM dots
#define NCOPY (16 + 840 + 12 + 36 + 4 + PKW2_N)

typedef __attribute__((ext_vector_type(8))) short short8;
typedef __attribute__((ext_vector_type(4))) float floatx4;

__device__ __forceinline__ float fast_sigmoid(float x) {
    return __builtin_amdgcn_rcpf(1.0f + __expf(-x));
}

__device__ __forceinline__ unsigned short f2bf(float f) {
    unsigned int u = __float_as_uint(f);
    u += 0x7FFFu + ((u >> 16) & 1u);   // round-to-nearest-even
    return (unsigned short)(u >> 16);
}

// ---------------- prep: wave-per-output 128-length dot products ----------------
__global__ __launch_bounds__(256) void prep_dots(
    const float* __restrict__ Wq, const float* __restrict__ bq,
    const float* __restrict__ Wk, const float* __restrict__ bk,
    const float* __restrict__ Wv, const float* __restrict__ bv,
    const float* __restrict__ W1, const float* __restrict__ b1,
    float* __restrict__ ws) {
    int lane = threadIdx.x & 63;
    int gidx = blockIdx.x * 4 + (threadIdx.x >> 6);
    if (gidx >= NDOT) return;

    const float* pa = bq;  const float* pb = bk;   // safe defaults
    int sa = 1, sb = 1;
    float scale = 1.0f, bias = 0.0f;
    bool zero = false;
    bool isbf = false; int bfpos = 0;

    if (gidx < O_M) {
        int idx = gidx;
        if (idx < O_GQQ) {
            int e = idx / STR, f = idx % STR;
            if (f < BAD) { pa = Wq + e; sa = BAD; pb = Wk + f; sb = BAD; }
            else zero = true;
        } else if (idx < O_GKK) {
            int j = idx - O_GQQ; int e = j / STR, f = j % STR;
            if (f < BAD && f <= e) { pa = Wq + e; sa = BAD; pb = Wq + f; sb = BAD; scale = (f == e) ? 1.0f : 2.0f; }
            else zero = true;
        } else if (idx < O_V1) {
            int j = idx - O_GKK; int e = j / STR, f = j % STR;
            if (f < BAD && f <= e) { pa = Wk + e; sa = BAD; pb = Wk + f; sb = BAD; scale = (f == e) ? 1.0f : 2.0f; }
            else zero = true;
        } else if (idx < O_V2) {
            int e = idx - O_V1;
            if (e < BAD) { pa = Wq + e; sa = BAD; pb = bk; }
            else zero = true;
        } else if (idx < O_VQ) {
            int e = idx - O_V2;
            if (e < BAD) { pa = Wk + e; sa = BAD; pb = bq; }
            else zero = true;
        } else if (idx < O_VK) {
            int e = idx - O_VQ;
            if (e < BAD) { pa = Wq + e; sa = BAD; pb = bq; }
            else zero = true;
        } else if (idx < O_C) {
            int e = idx - O_VK;
            if (e < BAD) { pa = Wk + e; sa = BAD; pb = bk; }
            else zero = true;
        } else {
            int j = idx - O_C;
            if (j == 0)      { pa = bq; pb = bk; }
            else if (j == 1) { pa = bq; pb = bq; }
            else if (j == 2) { pa = bk; pb = bk; }
            else zero = true;
        }
    } else {
        // pkM B-frag: B[k][n], n = tile*16 + (l&15), k = (l>>4)*8 + j
        int p = gidx - O_M;
        isbf = true; bfpos = p;
        int l2 = (p >> 3) & 63, j = p & 7;
        int n = (p >> 9) * 16 + (l2 & 15);
        int k = ((l2 >> 4) << 3) + j;
        if (k < BAD)       { pa = W1 + n * VD; pb = Wv + k; sb = BAD; scale = 2.0f; }
        else if (k == BAD) { pa = W1 + n * VD; pb = bv; scale = 2.0f; bias = 2.0f * b1[n]; }
        else zero = true;
    }

    float s = 0.0f;
    if (!zero)
        s = pa[sa * lane] * pb[sb * lane] + pa[sa * (lane + 64)] * pb[sb * (lane + 64)];
    #pragma unroll
    for (int off = 1; off < 64; off <<= 1) s += __shfl_xor(s, off);
    float val = zero ? 0.0f : (s * scale + bias);
    if (lane == 0) {
        if (isbf) ((unsigned short*)(ws + O_PKM))[bfpos] = f2bf(val);
        else ws[gidx] = val;
    }
}

__global__ __launch_bounds__(256) void prep_copy(
    const float* __restrict__ W2, const float* __restrict__ b2,
    const float* __restrict__ Wc1, const float* __restrict__ bc1,
    const float* __restrict__ Wc2, const float* __restrict__ bc2,
    float* __restrict__ ws) {
    int c = blockIdx.x * 256 + threadIdx.x;
    if (c >= NCOPY) return;
    if (c < 16) { ws[O_B2 + c] = b2[c]; return; }
    c -= 16;
    if (c < 840) {
        int m = c / 84, r = c % 84, i = r / STR, f = r % STR;
        ws[O_WC1 + c] = (f < BAD) ? Wc1[m * (NBK * BAD) + i * BAD + f] : 0.0f;
        return;
    }
    c -= 840;
    if (c < 12) { ws[O_BC1 + c] = (c < CM) ? bc1[c] : 0.0f; return; }
    c -= 12;
    if (c < 36) { int o = c / 12, mm = c % 12; ws[O_WC2 + c] = (mm < CM) ? Wc2[o * CM + mm] : 0.0f; return; }
    c -= 36;
    if (c < 4) { ws[O_BC2 + c] = (c < 3) ? bc2[c] : 0.0f; return; }
    c -= 4;
    // pkW2 B-frag: B[k][o], o = l&15, k = kt*32 + (l>>4)*8 + j
    int kt = c >> 9, l = (c >> 3) & 63, j = c & 7;
    int o = l & 15;
    int k = kt * 32 + ((l >> 4) << 3) + j;
    ((unsigned short*)(ws + O_PKW2))[c] = f2bf(W2[o * VD + k]);
}

// ---------------- fused main kernel: WAVE-PARITY SPLIT phase 1 ----------------
// Block = 128 threads = 2 waves over 64 elements; 1 lane per element per wave.
// h_u = wave id (SGPR via readfirstlane) -> ALL weight addresses are
// wave-uniform -> s_load/constant-cache channel (r5's lane-level h made the
// same reads per-lane VMEM: ~350 global_loads/wave, the dominant stall).
// Work split (identical to r5, so numerics are bit-identical):
//   wave0: GQQ triangle(qn2), s1/dq, even-e num rows + e24, conf m0-4, a_tilde e0-11
//   wave1: GKK triangle(kn2), s2/dk, odd-e num rows,        conf m5-9, a_tilde e12-24
// Pair exchange (20 fp32/elem) via LDS buffer ALIASED onto the At region
// (lifetimes disjoint; 3 barriers on 2 symmetric waves).
// Phase 2: verified swapped-MFMA + register-bpermute path, 6 tiles/wave.
__global__ __launch_bounds__(128) void main_kernel(
    const float* __restrict__ states, const float* __restrict__ action,
    const int* __restrict__ block_id,
    const float* __restrict__ ws, float* __restrict__ out) {
    __shared__ __align__(16) unsigned short At[192 * 40];   // 15360 B (Ex aliased: 10752 B)

    int t = threadIdx.x;
    int lane = t & 63;
    int h_u = __builtin_amdgcn_readfirstlane(t >> 6);   // wave id 0/1, SGPR
    long elem = (long)blockIdx.x * 64 + lane;

    const float* st = states + elem * (NBK * SS);
    const float* ac = action + elem * NA;
    const int* bid = block_id + elem * NBK;

    // ---- build ba[3][25] (full copy per lane; compile-time indices) ----
    float ba[NBK * BAD];
    #pragma unroll
    for (int i = 0; i < NBK; ++i) {
        const float4* s4 = (const float4*)(st + i * SS);
        #pragma unroll
        for (int w4 = 0; w4 < 4; ++w4) {
            float4 v = s4[w4];
            ba[i * BAD + w4 * 4 + 0] = v.x;
            ba[i * BAD + w4 * 4 + 1] = v.y;
            ba[i * BAD + w4 * 4 + 2] = v.z;
            ba[i * BAD + w4 * 4 + 3] = v.w;
        }
        bool sel = (bid[i] == 1);
        #pragma unroll
        for (int c = 0; c < NA; ++c)
            ba[i * BAD + SS + c] = sel ? ac[c] : -1.0f;
    }

    // ---- confidence MLP hidden: wave h computes m in [5h, 5h+5) ----
    float hp[5];
    {
        const float* wc = ws + O_WC1 + h_u * 5 * 84;    // uniform base
        const float* bc = ws + O_BC1 + h_u * 5;
        #pragma unroll
        for (int k = 0; k < 5; ++k) {
            float s = bc[k];
            #pragma unroll
            for (int i = 0; i < NBK; ++i)
                #pragma unroll
                for (int f = 0; f < BAD; ++f)
                    s += wc[k * 84 + i * STR + f] * ba[i * BAD + f];
            hp[k] = fast_sigmoid(s);
        }
    }

    // ---- linear terms: wave0 -> s1(V1), dq(VQ); wave1 -> s2(V2), dk(VK) ----
    float sl[NBK], dd[NBK];
    {
        const float* vA = ws + (h_u ? O_V2 : O_V1);
        const float* vB = ws + (h_u ? O_VK : O_VQ);
        #pragma unroll
        for (int p = 0; p < NBK; ++p) {
            float sA = 0.f, sB = 0.f;
            #pragma unroll
            for (int e = 0; e < BAD; ++e) {
                float b = ba[p * BAD + e];
                sA = fmaf(vA[e], b, sA);
                sB = fmaf(vB[e], b, sB);
            }
            sl[p] = sA; dd[p] = sB;
        }
    }

    // ---- bilinear numerator partials: wave0 even e + e24, wave1 odd e ----
    float nm[NBK][NBK] = {{0.f,0.f,0.f},{0.f,0.f,0.f},{0.f,0.f,0.f}};
    if (h_u == 0) {
        #pragma unroll
        for (int ii = 0; ii < 13; ++ii) {
            const int e = (ii < 12) ? (2 * ii) : 24;
            const float* grow = ws + O_GQK + e * STR;   // uniform
            float t0 = 0.f, t1 = 0.f, t2 = 0.f;
            #pragma unroll
            for (int f = 0; f < BAD; ++f) {
                float g = grow[f];
                t0 = fmaf(g, ba[0 * BAD + f], t0);
                t1 = fmaf(g, ba[1 * BAD + f], t1);
                t2 = fmaf(g, ba[2 * BAD + f], t2);
            }
            #pragma unroll
            for (int i = 0; i < NBK; ++i) {
                float be = ba[i * BAD + e];
                nm[i][0] = fmaf(be, t0, nm[i][0]);
                nm[i][1] = fmaf(be, t1, nm[i][1]);
                nm[i][2] = fmaf(be, t2, nm[i][2]);
            }
        }
    } else {
        #pragma unroll
        for (int ii = 0; ii < 12; ++ii) {
            const int e = 2 * ii + 1;
            const float* grow = ws + O_GQK + e * STR;   // uniform
            float t0 = 0.f, t1 = 0.f, t2 = 0.f;
            #pragma unroll
            for (int f = 0; f < BAD; ++f) {
                float g = grow[f];
                t0 = fmaf(g, ba[0 * BAD + f], t0);
                t1 = fmaf(g, ba[1 * BAD + f], t1);
                t2 = fmaf(g, ba[2 * BAD + f], t2);
            }
            #pragma unroll
            for (int i = 0; i < NBK; ++i) {
                float be = ba[i * BAD + e];
                nm[i][0] = fmaf(be, t0, nm[i][0]);
                nm[i][1] = fmaf(be, t1, nm[i][1]);
                nm[i][2] = fmaf(be, t2, nm[i][2]);
            }
        }
    }

    // ---- quadratic triangle: wave0 GQQ (qn2), wave1 GKK (kn2) ----
    float rn[NBK];
    {
        const float* gt = ws + (h_u ? O_GKK : O_GQQ);   // uniform
        float sn2[NBK] = {0.f, 0.f, 0.f};
        #pragma unroll
        for (int e = 0; e < BAD; ++e) {
            float p0 = 0.f, p1 = 0.f, p2 = 0.f;
            #pragma unroll
            for (int f = 0; f <= e; ++f) {
                float g = gt[e * STR + f];
                p0 = fmaf(g, ba[0 * BAD + f], p0);
                p1 = fmaf(g, ba[1 * BAD + f], p1);
                p2 = fmaf(g, ba[2 * BAD + f], p2);
            }
            sn2[0] = fmaf(ba[0 * BAD + e], p0, sn2[0]);
            sn2[1] = fmaf(ba[1 * BAD + e], p1, sn2[1]);
            sn2[2] = fmaf(ba[2 * BAD + e], p2, sn2[2]);
        }
        float cc = ws[O_C + 1 + h_u];                   // cq or ck
        #pragma unroll
        for (int p = 0; p < NBK; ++p) {
            sn2[p] += 2.0f * dd[p] + cc;
            rn[p] = __builtin_amdgcn_sqrtf(fmaxf(sn2[p], 0.0f));
        }
    }

    // ---- cross-wave exchange via LDS (aliased onto At; stride 21 words) ----
    float* exf = (float*)At;
    {
        float* my = exf + (h_u * 64 + lane) * 21;
        my[0] = rn[0]; my[1] = rn[1]; my[2] = rn[2];
        my[3] = sl[0]; my[4] = sl[1]; my[5] = sl[2];
        #pragma unroll
        for (int i = 0; i < NBK; ++i)
            #pragma unroll
            for (int j = 0; j < NBK; ++j)
                my[6 + i * 3 + j] = nm[i][j];
        #pragma unroll
        for (int k = 0; k < 5; ++k) my[15 + k] = hp[k];
    }
    __syncthreads();

    float orn[NBK], osl[NBK], ohp[5];
    {
        const float* ot = exf + ((1 - h_u) * 64 + lane) * 21;
        orn[0] = ot[0]; orn[1] = ot[1]; orn[2] = ot[2];
        osl[0] = ot[3]; osl[1] = ot[4]; osl[2] = ot[5];
        #pragma unroll
        for (int i = 0; i < NBK; ++i)
            #pragma unroll
            for (int j = 0; j < NBK; ++j)
                nm[i][j] += ot[6 + i * 3 + j];
        #pragma unroll
        for (int k = 0; k < 5; ++k) ohp[k] = ot[15 + k];
    }
    __syncthreads();   // all Ex reads done before At is overwritten

    // ---- conf output (wave0 only; hm = [hp m0-4, ohp m5-9]) ----
    if (h_u == 0) {
        float* op = out + elem * OUTD;
        #pragma unroll
        for (int o = 0; o < 3; ++o) {
            float s = ws[O_BC2 + o];
            #pragma unroll
            for (int m = 0; m < 5; ++m) s += ws[O_WC2 + o * 12 + m] * hp[m];
            #pragma unroll
            for (int m = 0; m < 5; ++m) s += ws[O_WC2 + o * 12 + 5 + m] * ohp[m];
            op[48 + o] = fast_sigmoid(s);
        }
    }

    // ---- assemble per-role scalars ----
    float s1v[NBK], s2v[NBK], qv[NBK], kv[NBK];
    #pragma unroll
    for (int p = 0; p < NBK; ++p) {
        s1v[p] = h_u ? osl[p] : sl[p];
        s2v[p] = h_u ? sl[p] : osl[p];
        qv[p]  = h_u ? orn[p] : rn[p];
        kv[p]  = h_u ? rn[p] : orn[p];
    }
    float c0 = ws[O_C + 0];

    // ---- softmax over j (duplicated on both waves; cheap) ----
    float att[NBK][NBK];
    #pragma unroll
    for (int i = 0; i < NBK; ++i) {
        float dv[NBK];
        #pragma unroll
        for (int j = 0; j < NBK; ++j)
            dv[j] = (nm[i][j] + s1v[i] + s2v[j] + c0) *
                    __builtin_amdgcn_rcpf(fmaxf(qv[i] * kv[j], EPS));
        float mx = fmaxf(dv[0], fmaxf(dv[1], dv[2]));
        float e0 = __expf(dv[0] - mx);
        float e1 = __expf(dv[1] - mx);
        float e2 = __expf(dv[2] - mx);
        float inv = __builtin_amdgcn_rcpf(e0 + e1 + e2);
        att[i][0] = e0 * inv;
        att[i][1] = e1 * inv;
        att[i][2] = e2 * inv;
    }

    // ---- a_tilde + bf16 pack + At write: e-range split by wave ----
    if (h_u == 0) {
        #pragma unroll
        for (int i = 0; i < NBK; ++i) {
            unsigned int* dst = (unsigned int*)&At[(lane * 3 + i) * 40];
            #pragma unroll
            for (int d = 0; d < 6; ++d) {
                float lo = ba[0 * BAD + 2 * d]     * att[i][0] + ba[1 * BAD + 2 * d]     * att[i][1] + ba[2 * BAD + 2 * d]     * att[i][2];
                float hi = ba[0 * BAD + 2 * d + 1] * att[i][0] + ba[1 * BAD + 2 * d + 1] * att[i][1] + ba[2 * BAD + 2 * d + 1] * att[i][2];
                dst[d] = (unsigned int)f2bf(lo) | ((unsigned int)f2bf(hi) << 16);
            }
            dst[13] = 0u; dst[14] = 0u; dst[15] = 0u;
        }
    } else {
        #pragma unroll
        for (int i = 0; i < NBK; ++i) {
            unsigned int* dst = (unsigned int*)&At[(lane * 3 + i) * 40];
            #pragma unroll
            for (int d = 0; d < 6; ++d) {
                float lo = ba[0 * BAD + 12 + 2 * d]     * att[i][0] + ba[1 * BAD + 12 + 2 * d]     * att[i][1] + ba[2 * BAD + 12 + 2 * d]     * att[i][2];
                float hi = ba[0 * BAD + 12 + 2 * d + 1] * att[i][0] + ba[1 * BAD + 12 + 2 * d + 1] * att[i][1] + ba[2 * BAD + 12 + 2 * d + 1] * att[i][2];
                dst[6 + d] = (unsigned int)f2bf(lo) | ((unsigned int)f2bf(hi) << 16);
            }
            float v24 = ba[0 * BAD + 24] * att[i][0] + ba[1 * BAD + 24] * att[i][1] + ba[2 * BAD + 24] * att[i][2];
            dst[12] = (unsigned int)f2bf(v24) | (0x3F80u << 16);
        }
    }

    __syncthreads();

    // ================= phase 2: MFMA (6 tiles per wave) =================
    {
        int m = lane & 15, q = lane >> 4;
        const short8* pkM = (const short8*)(ws + O_PKM);
        const short8* pkW2 = (const short8*)(ws + O_PKW2);
        float b2v = ws[O_B2 + m];
        long blockbase = (long)blockIdx.x * 64;
        int addrA = ((q & 1) ? (m + 32) : m) << 2;
        int addrB = addrA + 64;
        bool hiSel = (q >= 2);

        for (int tt = 0; tt < 6; ++tt) {
            int tile = h_u * 6 + tt;          // rows tile*16 .. +15 (0..191)
            short8 af = *(const short8*)&At[(tile * 16 + m) * 40 + q * 8];
            floatx4 accT[8];
            #pragma unroll
            for (int nt = 0; nt < 8; ++nt) {
                floatx4 z = {0.f, 0.f, 0.f, 0.f};
                accT[nt] = __builtin_amdgcn_mfma_f32_16x16x32_bf16(pkM[nt * 64 + lane], af, z, 0, 0, 0);
            }
            unsigned int pk[8][2];
            #pragma unroll
            for (int nt = 0; nt < 8; ++nt) {
                float x0 = fmaf(-2.0f, __builtin_amdgcn_rcpf(1.0f + __expf(accT[nt][0])), 1.0f);
                float x1 = fmaf(-2.0f, __builtin_amdgcn_rcpf(1.0f + __expf(accT[nt][1])), 1.0f);
                float x2 = fmaf(-2.0f, __builtin_amdgcn_rcpf(1.0f + __expf(accT[nt][2])), 1.0f);
                float x3 = fmaf(-2.0f, __builtin_amdgcn_rcpf(1.0f + __expf(accT[nt][3])), 1.0f);
                asm("v_cvt_pk_bf16_f32 %0, %1, %2" : "=v"(pk[nt][0]) : "v"(x0), "v"(x1));
                asm("v_cvt_pk_bf16_f32 %0, %1, %2" : "=v"(pk[nt][1]) : "v"(x2), "v"(x3));
            }
            floatx4 acc2 = {0.f, 0.f, 0.f, 0.f};
            #pragma unroll
            for (int kt = 0; kt < 4; ++kt) {
                int lo0 = __builtin_amdgcn_ds_bpermute(addrA, (int)pk[2 * kt][0]);
                int hi0 = __builtin_amdgcn_ds_bpermute(addrA, (int)pk[2 * kt + 1][0]);
                int lo1 = __builtin_amdgcn_ds_bpermute(addrA, (int)pk[2 * kt][1]);
                int hi1 = __builtin_amdgcn_ds_bpermute(addrA, (int)pk[2 * kt + 1][1]);
                int lo2 = __builtin_amdgcn_ds_bpermute(addrB, (int)pk[2 * kt][0]);
                int hi2 = __builtin_amdgcn_ds_bpermute(addrB, (int)pk[2 * kt + 1][0]);
                int lo3 = __builtin_amdgcn_ds_bpermute(addrB, (int)pk[2 * kt][1]);
                int hi3 = __builtin_amdgcn_ds_bpermute(addrB, (int)pk[2 * kt + 1][1]);
                union { unsigned int u[4]; short8 s; } a2u;
                a2u.u[0] = (unsigned int)(hiSel ? hi0 : lo0);
                a2u.u[1] = (unsigned int)(hiSel ? hi1 : lo1);
                a2u.u[2] = (unsigned int)(hiSel ? hi2 : lo2);
                a2u.u[3] = (unsigned int)(hiSel ? hi3 : lo3);
                acc2 = __builtin_amdgcn_mfma_f32_16x16x32_bf16(a2u.s, pkW2[kt * 64 + lane], acc2, 0, 0, 0);
            }
            #pragma unroll
            for (int rr = 0; rr < 4; ++rr) {
                int lrow = tile * 16 + q * 4 + rr;     // 0..191
                int et = lrow / 3, i = lrow - et * 3;
                long ge = blockbase + et;
                float base = states[ge * 48 + i * 16 + m];
                out[ge * OUTD + i * 16 + m] = acc2[rr] + base + b2v;
            }
        }
    }
}

extern "C" void kernel_launch(void* const* d_in, const int* in_sizes, int n_in,
                              void* d_out, int out_size, void* d_ws, size_t ws_size,
                              hipStream_t stream) {
    const float* states = (const float*)d_in[0];
    const float* action = (const float*)d_in[1];
    const int* block_id = (const int*)d_in[2];
    const float* Wq = (const float*)d_in[3];
    const float* bq = (const float*)d_in[4];
    const float* Wk = (const float*)d_in[5];
    const float* bk = (const float*)d_in[6];
    const float* Wv = (const float*)d_in[7];
    const float* bv = (const float*)d_in[8];
    const float* W1 = (const float*)d_in[9];
    const float* b1 = (const float*)d_in[10];
    const float* W2 = (const float*)d_in[11];
    const float* b2 = (const float*)d_in[12];
    const float* Wc1 = (const float*)d_in[13];
    const float* bc1 = (const float*)d_in[14];
    const float* Wc2 = (const float*)d_in[15];
    const float* bc2 = (const float*)d_in[16];
    float* out = (float*)d_out;
    float* ws = (float*)d_ws;

    hipLaunchKernelGGL(prep_dots, dim3((NDOT + 3) / 4), dim3(256), 0, stream,
                       Wq, bq, Wk, bk, Wv, bv, W1, b1, ws);
    hipLaunchKernelGGL(prep_copy, dim3((NCOPY + 255) / 256), dim3(256), 0, stream,
                       W2, b2, Wc1, bc1, Wc2, bc2, ws);
    hipLaunchKernelGGL(main_kernel, dim3(BTOT / 64), dim3(128), 0, stream,
                       states, action, block_id, ws, out);
}

// Round 7
// 169.700 us; speedup vs baseline: 1.0123x; 1.0123x over previous
//
#include <hip/hip_runtime.h>
#include <math.h>

#define BTOT 131072
#define NBK 3
#define SS 16
#define NA 9
#define BAD 25      // SS+NA
#define STR 28      // padded row stride in the fp32 weight image
#define VD 128
#define CM 10
#define OUTD 51     // NBK*SS + 3
#define EPS 1e-8f

// ---- fp32 folded-weight image (float offsets in ws) ----
#define O_GQK  0        // 25 x 28  full Wq^T Wk
#define O_GQQ  700      // 25 x 28  lower-tri (off-diag x2) of Wq^T Wq
#define O_GKK  1400     // 25 x 28  lower-tri (off-diag x2) of Wk^T Wk
#define O_V1   2100     // 28: Wq^T bk
#define O_V2   2128     // 28: Wk^T bq
#define O_VQ   2156     // 28: Wq^T bq
#define O_VK   2184     // 28: Wk^T bk
#define O_C    2212     // c0, cq, ck, pad
#define O_M    2216     // (dead region)
#define O_B2   7976     // 16
#define O_WC1  7992     // 10 x 84
#define O_BC1  8832     // 12
#define O_WC2  8844     // 3 x 12
#define O_BC2  8880     // 4
#define LDS_F  8884
// ---- bf16 MFMA-packed B-fragments appended after the fp32 image ----
#define O_PKM  LDS_F          // 4096 ushorts = 2048 floats
#define O_PKW2 (LDS_F + 2048) // 2048 ushorts = 1024 floats
#define PKM_N  4096
#define PKW2_N 2048

#define NDOT  (O_M + PKM_N)   // 2216 fp32 dots + 4096 pkM dots
#define NCOPY (16 + 840 + 12 + 36 + 4 + PKW2_N)

typedef __attribute__((ext_vector_type(8))) short short8;
typedef __attribute__((ext_vector_type(4))) float floatx4;
typedef __attribute__((ext_vector_type(2))) float float2v;

__device__ __forceinline__ float fast_sigmoid(float x) {
    return __builtin_amdgcn_rcpf(1.0f + __expf(-x));
}

__device__ __forceinline__ unsigned short f2bf(float f) {
    unsigned int u = __float_as_uint(f);
    u += 0x7FFFu + ((u >> 16) & 1u);   // round-to-nearest-even
    return (unsigned short)(u >> 16);
}

// VOP3P packed fp32: 2 FMAs / instruction. gfx950's 157 TF fp32 peak is only
// reachable through these; hipcc does not auto-generate them.
__device__ __forceinline__ float2v pk_fma(float2v a, float2v b, float2v c) {
    float2v d;
    asm("v_pk_fma_f32 %0, %1, %2, %3" : "=v"(d) : "v"(a), "v"(b), "v"(c));
    return d;
}
__device__ __forceinline__ float2v pk_mul(float2v a, float2v b) {
    float2v d;
    asm("v_pk_mul_f32 %0, %1, %2" : "=v"(d) : "v"(a), "v"(b));
    return d;
}
__device__ __forceinline__ unsigned int cvt_pk_bf16(float lo, float hi) {
    unsigned int r;
    asm("v_cvt_pk_bf16_f32 %0, %1, %2" : "=v"(r) : "v"(lo), "v"(hi));
    return r;
}

// ---------------- prep: wave-per-output 128-length dot products ----------------
__global__ __launch_bounds__(256) void prep_dots(
    const float* __restrict__ Wq, const float* __restrict__ bq,
    const float* __restrict__ Wk, const float* __restrict__ bk,
    const float* __restrict__ Wv, const float* __restrict__ bv,
    const float* __restrict__ W1, const float* __restrict__ b1,
    float* __restrict__ ws) {
    int lane = threadIdx.x & 63;
    int gidx = blockIdx.x * 4 + (threadIdx.x >> 6);
    if (gidx >= NDOT) return;

    const float* pa = bq;  const float* pb = bk;   // safe defaults
    int sa = 1, sb = 1;
    float scale = 1.0f, bias = 0.0f;
    bool zero = false;
    bool isbf = false; int bfpos = 0;

    if (gidx < O_M) {
        int idx = gidx;
        if (idx < O_GQQ) {
            int e = idx / STR, f = idx % STR;
            if (f < BAD) { pa = Wq + e; sa = BAD; pb = Wk + f; sb = BAD; }
            else zero = true;
        } else if (idx < O_GKK) {
            int j = idx - O_GQQ; int e = j / STR, f = j % STR;
            if (f < BAD && f <= e) { pa = Wq + e; sa = BAD; pb = Wq + f; sb = BAD; scale = (f == e) ? 1.0f : 2.0f; }
            else zero = true;
        } else if (idx < O_V1) {
            int j = idx - O_GKK; int e = j / STR, f = j % STR;
            if (f < BAD && f <= e) { pa = Wk + e; sa = BAD; pb = Wk + f; sb = BAD; scale = (f == e) ? 1.0f : 2.0f; }
            else zero = true;
        } else if (idx < O_V2) {
            int e = idx - O_V1;
            if (e < BAD) { pa = Wq + e; sa = BAD; pb = bk; }
            else zero = true;
        } else if (idx < O_VQ) {
            int e = idx - O_V2;
            if (e < BAD) { pa = Wk + e; sa = BAD; pb = bq; }
            else zero = true;
        } else if (idx < O_VK) {
            int e = idx - O_VQ;
            if (e < BAD) { pa = Wq + e; sa = BAD; pb = bq; }
            else zero = true;
        } else if (idx < O_C) {
            int e = idx - O_VK;
            if (e < BAD) { pa = Wk + e; sa = BAD; pb = bk; }
            else zero = true;
        } else {
            int j = idx - O_C;
            if (j == 0)      { pa = bq; pb = bk; }
            else if (j == 1) { pa = bq; pb = bq; }
            else if (j == 2) { pa = bk; pb = bk; }
            else zero = true;
        }
    } else {
        // pkM B-frag: B[k][n], n = tile*16 + (l&15), k = (l>>4)*8 + j
        int p = gidx - O_M;
        isbf = true; bfpos = p;
        int l2 = (p >> 3) & 63, j = p & 7;
        int n = (p >> 9) * 16 + (l2 & 15);
        int k = ((l2 >> 4) << 3) + j;
        if (k < BAD)       { pa = W1 + n * VD; pb = Wv + k; sb = BAD; scale = 2.0f; }
        else if (k == BAD) { pa = W1 + n * VD; pb = bv; scale = 2.0f; bias = 2.0f * b1[n]; }
        else zero = true;
    }

    float s = 0.0f;
    if (!zero)
        s = pa[sa * lane] * pb[sb * lane] + pa[sa * (lane + 64)] * pb[sb * (lane + 64)];
    #pragma unroll
    for (int off = 1; off < 64; off <<= 1) s += __shfl_xor(s, off);
    float val = zero ? 0.0f : (s * scale + bias);
    if (lane == 0) {
        if (isbf) ((unsigned short*)(ws + O_PKM))[bfpos] = f2bf(val);
        else ws[gidx] = val;
    }
}

__global__ __launch_bounds__(256) void prep_copy(
    const float* __restrict__ W2, const float* __restrict__ b2,
    const float* __restrict__ Wc1, const float* __restrict__ bc1,
    const float* __restrict__ Wc2, const float* __restrict__ bc2,
    float* __restrict__ ws) {
    int c = blockIdx.x * 256 + threadIdx.x;
    if (c >= NCOPY) return;
    if (c < 16) { ws[O_B2 + c] = b2[c]; return; }
    c -= 16;
    if (c < 840) {
        int m = c / 84, r = c % 84, i = r / STR, f = r % STR;
        ws[O_WC1 + c] = (f < BAD) ? Wc1[m * (NBK * BAD) + i * BAD + f] : 0.0f;
        return;
    }
    c -= 840;
    if (c < 12) { ws[O_BC1 + c] = (c < CM) ? bc1[c] : 0.0f; return; }
    c -= 12;
    if (c < 36) { int o = c / 12, mm = c % 12; ws[O_WC2 + c] = (mm < CM) ? Wc2[o * CM + mm] : 0.0f; return; }
    c -= 36;
    if (c < 4) { ws[O_BC2 + c] = (c < 3) ? bc2[c] : 0.0f; return; }
    c -= 4;
    // pkW2 B-frag: B[k][o], o = l&15, k = kt*32 + (l>>4)*8 + j
    int kt = c >> 9, l = (c >> 3) & 63, j = c & 7;
    int o = l & 15;
    int k = kt * 32 + ((l >> 4) << 3) + j;
    ((unsigned short*)(ws + O_PKW2))[c] = f2bf(W2[o * VD + k]);
}

// ---------------- fused main kernel: LANE-PAIR SPLIT + PACKED FP32 ----------
// Structure identical to round 5 (70.2 us verified): 2 lanes per element
// (h = t&1), work-split phase 1, shfl_xor pair exchange, verified MFMA phase 2.
// New: all heavy phase-1 FMA chains run on v_pk_fma_f32 (2 FMA/instr) with ba
// held as reg-resident float2 pairs (ba2[3][13], constant-indexed), and the
// a_tilde bf16 pack uses v_cvt_pk_bf16_f32 (bit-identical RNE to f2bf).
// This cuts the phase-1 issued-instruction stream ~0.6x; rounds 1-6 showed
// time ~ per-wave instruction count x constant stall factor.
__global__ __launch_bounds__(256) void main_kernel(
    const float* __restrict__ states, const float* __restrict__ action,
    const int* __restrict__ block_id,
    const float* __restrict__ ws, float* __restrict__ out) {
    __shared__ __align__(16) unsigned short At[384 * 40];   // 30720 B

    int t = threadIdx.x;
    int lane = t & 63;
    int h = t & 1;
    int le = t >> 1;                        // local element 0..127
    long elem = (long)blockIdx.x * 128 + le;

    const float* st = states + elem * (NBK * SS);
    const float* ac = action + elem * NA;
    const int* bid = block_id + elem * NBK;

    // ---- build ba as float2 pairs: ba2[i][k] = {ba[2k], ba[2k+1]}, pad .y=0 at k=12
    float2v ba2[NBK][13];
    #pragma unroll
    for (int i = 0; i < NBK; ++i) {
        const float4* s4 = (const float4*)(st + i * SS);
        float4 v0 = s4[0], v1 = s4[1], v2 = s4[2], v3 = s4[3];
        ba2[i][0] = float2v{v0.x, v0.y}; ba2[i][1] = float2v{v0.z, v0.w};
        ba2[i][2] = float2v{v1.x, v1.y}; ba2[i][3] = float2v{v1.z, v1.w};
        ba2[i][4] = float2v{v2.x, v2.y}; ba2[i][5] = float2v{v2.z, v2.w};
        ba2[i][6] = float2v{v3.x, v3.y}; ba2[i][7] = float2v{v3.z, v3.w};
        bool sel = (bid[i] == 1);
        float av[9];
        #pragma unroll
        for (int c = 0; c < 9; ++c) av[c] = sel ? ac[c] : -1.0f;
        ba2[i][8]  = float2v{av[0], av[1]};
        ba2[i][9]  = float2v{av[2], av[3]};
        ba2[i][10] = float2v{av[4], av[5]};
        ba2[i][11] = float2v{av[6], av[7]};
        ba2[i][12] = float2v{av[8], 0.0f};
    }

    // ---- confidence MLP: h computes its 5 hidden units (packed dots) ----
    // pair k=12 covers f=24,25: wc[f=25]=0 and ba2[.][12].y=0 -> exact.
    {
        const float* wc = ws + O_WC1 + h * 5 * 84;   // per-lane base
        const float* bc = ws + O_BC1 + h * 5;
        float hp[5];
        #pragma unroll
        for (int k = 0; k < 5; ++k) {
            float2v a2 = {0.f, 0.f};
            #pragma unroll
            for (int i = 0; i < NBK; ++i) {
                const float2v* w2 = (const float2v*)(wc + k * 84 + i * STR);
                #pragma unroll
                for (int p = 0; p < 13; ++p) a2 = pk_fma(w2[p], ba2[i][p], a2);
            }
            hp[k] = fast_sigmoid(bc[k] + a2.x + a2.y);
        }
        float op5[5];
        #pragma unroll
        for (int k = 0; k < 5; ++k) op5[k] = __shfl_xor(hp[k], 1);
        if (h == 0) {
            float* op = out + elem * OUTD;
            #pragma unroll
            for (int o = 0; o < 3; ++o) {
                float s = ws[O_BC2 + o];
                #pragma unroll
                for (int m = 0; m < 5; ++m) s += ws[O_WC2 + o * 12 + m] * hp[m];
                #pragma unroll
                for (int m = 0; m < 5; ++m) s += ws[O_WC2 + o * 12 + 5 + m] * op5[m];
                op[48 + o] = fast_sigmoid(s);
            }
        }
    }

    // ---- linear terms (packed): h=0 -> s1(V1), dq(VQ); h=1 -> s2(V2), dk(VK)
    float sl[NBK], dd[NBK];
    {
        const float2v* vA2 = (const float2v*)(ws + (h ? O_V2 : O_V1));
        const float2v* vB2 = (const float2v*)(ws + (h ? O_VK : O_VQ));
        #pragma unroll
        for (int p = 0; p < NBK; ++p) {
            float2v sA = {0.f, 0.f}, sB = {0.f, 0.f};
            #pragma unroll
            for (int k = 0; k < 13; ++k) {
                sA = pk_fma(vA2[k], ba2[p][k], sA);
                sB = pk_fma(vB2[k], ba2[p][k], sB);
            }
            sl[p] = sA.x + sA.y; dd[p] = sB.x + sB.y;
        }
    }

    // ---- bilinear numerators (packed rows): h=0 even e + e24, h=1 odd e ----
    float nm[NBK][NBK] = {{0.f,0.f,0.f},{0.f,0.f,0.f},{0.f,0.f,0.f}};
    {
        const float* gq = ws + O_GQK + h * STR;   // per-lane base (row h)
        #pragma unroll
        for (int i13 = 0; i13 < 13; ++i13) {
            const float* grow = (i13 == 12) ? (ws + O_GQK + 24 * STR)
                                            : (gq + i13 * 2 * STR);
            const float2v* g2 = (const float2v*)grow;
            float2v t20 = {0.f, 0.f}, t21 = {0.f, 0.f}, t22 = {0.f, 0.f};
            #pragma unroll
            for (int p = 0; p < 13; ++p) {
                t20 = pk_fma(g2[p], ba2[0][p], t20);
                t21 = pk_fma(g2[p], ba2[1][p], t21);
                t22 = pk_fma(g2[p], ba2[2][p], t22);
            }
            float t0 = t20.x + t20.y, t1 = t21.x + t21.y, t2s = t22.x + t22.y;
            #pragma unroll
            for (int i = 0; i < NBK; ++i) {
                float be;
                if (i13 == 12) be = ba2[i][12].x * (1.0f - (float)h);
                else           be = h ? ba2[i][i13].y : ba2[i][i13].x;
                nm[i][0] = fmaf(be, t0, nm[i][0]);
                nm[i][1] = fmaf(be, t1, nm[i][1]);
                nm[i][2] = fmaf(be, t2s, nm[i][2]);
            }
        }
        // combine halves
        #pragma unroll
        for (int i = 0; i < NBK; ++i)
            #pragma unroll
            for (int j = 0; j < NBK; ++j)
                nm[i][j] += __shfl_xor(nm[i][j], 1);
    }

    // ---- quadratic triangle (packed): h=0 GQQ (qn2), h=1 GKK (kn2) ----
    float rn[NBK];
    {
        const float* gt = ws + (h ? O_GKK : O_GQQ);   // per-lane base
        float sn2[NBK] = {0.f, 0.f, 0.f};
        #pragma unroll
        for (int e = 0; e < BAD; ++e) {
            const float2v* g2 = (const float2v*)(gt + e * STR);
            float2v q20 = {0.f, 0.f}, q21 = {0.f, 0.f}, q22 = {0.f, 0.f};
            #pragma unroll
            for (int k = 0; k < (e + 1) / 2; ++k) {
                q20 = pk_fma(g2[k], ba2[0][k], q20);
                q21 = pk_fma(g2[k], ba2[1][k], q21);
                q22 = pk_fma(g2[k], ba2[2][k], q22);
            }
            float p0 = q20.x + q20.y, p1 = q21.x + q21.y, p2 = q22.x + q22.y;
            if ((e & 1) == 0) {   // tail f = e (even e)
                float g = gt[e * STR + e];
                p0 = fmaf(g, ba2[0][e / 2].x, p0);
                p1 = fmaf(g, ba2[1][e / 2].x, p1);
                p2 = fmaf(g, ba2[2][e / 2].x, p2);
            }
            float be0 = (e & 1) ? ba2[0][e / 2].y : ba2[0][e / 2].x;
            float be1 = (e & 1) ? ba2[1][e / 2].y : ba2[1][e / 2].x;
            float be2 = (e & 1) ? ba2[2][e / 2].y : ba2[2][e / 2].x;
            sn2[0] = fmaf(be0, p0, sn2[0]);
            sn2[1] = fmaf(be1, p1, sn2[1]);
            sn2[2] = fmaf(be2, p2, sn2[2]);
        }
        float cc = ws[O_C + 1 + h];                   // cq or ck
        #pragma unroll
        for (int p = 0; p < NBK; ++p) {
            sn2[p] += 2.0f * dd[p] + cc;
            rn[p] = __builtin_amdgcn_sqrtf(fmaxf(sn2[p], 0.0f));
        }
    }

    // ---- exchange row norms and linear sums across the pair ----
    float orn[NBK], osl[NBK];
    #pragma unroll
    for (int p = 0; p < NBK; ++p) {
        orn[p] = __shfl_xor(rn[p], 1);
        osl[p] = __shfl_xor(sl[p], 1);
    }
    float s1v[NBK], s2v[NBK], qv[NBK], kv[NBK];
    #pragma unroll
    for (int p = 0; p < NBK; ++p) {
        s1v[p] = h ? osl[p] : sl[p];
        s2v[p] = h ? sl[p] : osl[p];
        qv[p]  = h ? orn[p] : rn[p];
        kv[p]  = h ? rn[p] : orn[p];
    }
    float c0 = ws[O_C + 0];

    // ---- softmax over j (duplicated on both lanes; cheap) ----
    float att[NBK][NBK];
    #pragma unroll
    for (int i = 0; i < NBK; ++i) {
        float dv[NBK];
        #pragma unroll
        for (int j = 0; j < NBK; ++j)
            dv[j] = (nm[i][j] + s1v[i] + s2v[j] + c0) *
                    __builtin_amdgcn_rcpf(fmaxf(qv[i] * kv[j], EPS));
        float mx = fmaxf(dv[0], fmaxf(dv[1], dv[2]));
        float e0 = __expf(dv[0] - mx);
        float e1 = __expf(dv[1] - mx);
        float e2 = __expf(dv[2] - mx);
        float inv = __builtin_amdgcn_rcpf(e0 + e1 + e2);
        att[i][0] = e0 * inv;
        att[i][1] = e1 * inv;
        att[i][2] = e2 * inv;
    }

    // ---- a_tilde (packed) + cvt_pk_bf16 + LDS write: e-range split ----
    // h=0: pairs 0..5 -> dwords 0..5 (+ zero dwords 13..15)
    // h=1: pairs 6..11 -> dwords 6..11; e24+bias -> dword 12
    #pragma unroll
    for (int i = 0; i < NBK; ++i) {
        unsigned int* dst = (unsigned int*)&At[(le * 3 + i) * 40];
        float2v w0 = {att[i][0], att[i][0]};
        float2v w1 = {att[i][1], att[i][1]};
        float2v w2d = {att[i][2], att[i][2]};
        #pragma unroll
        for (int d = 0; d < 6; ++d) {
            float2v va = pk_fma(ba2[0][d], w0, pk_fma(ba2[1][d], w1, pk_mul(ba2[2][d], w2d)));
            float2v vb = pk_fma(ba2[0][6 + d], w0, pk_fma(ba2[1][6 + d], w1, pk_mul(ba2[2][6 + d], w2d)));
            float lo = h ? vb.x : va.x;
            float hi = h ? vb.y : va.y;
            dst[h * 6 + d] = cvt_pk_bf16(lo, hi);
        }
        if (h) {
            float v24 = ba2[0][12].x * att[i][0] + ba2[1][12].x * att[i][1] + ba2[2][12].x * att[i][2];
            dst[12] = cvt_pk_bf16(v24, 1.0f);   // hi = bf16(1.0) = 0x3F80
        } else {
            dst[13] = 0u; dst[14] = 0u; dst[15] = 0u;
        }
    }

    // At is wave-private: pair lanes and phase-2 tiles belong to the same wave.
    asm volatile("s_waitcnt lgkmcnt(0)" ::: "memory");

    // ================= phase 2: MFMA (6 tiles per wave, verified path) =======
    {
        int w = t >> 6;
        int m = lane & 15, q = lane >> 4;
        const short8* pkM = (const short8*)(ws + O_PKM);
        const short8* pkW2 = (const short8*)(ws + O_PKW2);
        float b2v = ws[O_B2 + m];
        long blockbase = (long)blockIdx.x * 128;
        int addrA = ((q & 1) ? (m + 32) : m) << 2;
        int addrB = addrA + 64;
        bool hiSel = (q >= 2);

        for (int tt = 0; tt < 6; ++tt) {
            int tile = w * 6 + tt;            // rows tile*16 .. +15 (0..383)
            short8 af = *(const short8*)&At[(tile * 16 + m) * 40 + q * 8];
            floatx4 accT[8];
            #pragma unroll
            for (int nt = 0; nt < 8; ++nt) {
                floatx4 z = {0.f, 0.f, 0.f, 0.f};
                accT[nt] = __builtin_amdgcn_mfma_f32_16x16x32_bf16(pkM[nt * 64 + lane], af, z, 0, 0, 0);
            }
            unsigned int pk[8][2];
            #pragma unroll
            for (int nt = 0; nt < 8; ++nt) {
                float x0 = fmaf(-2.0f, __builtin_amdgcn_rcpf(1.0f + __expf(accT[nt][0])), 1.0f);
                float x1 = fmaf(-2.0f, __builtin_amdgcn_rcpf(1.0f + __expf(accT[nt][1])), 1.0f);
                float x2 = fmaf(-2.0f, __builtin_amdgcn_rcpf(1.0f + __expf(accT[nt][2])), 1.0f);
                float x3 = fmaf(-2.0f, __builtin_amdgcn_rcpf(1.0f + __expf(accT[nt][3])), 1.0f);
                pk[nt][0] = cvt_pk_bf16(x0, x1);
                pk[nt][1] = cvt_pk_bf16(x2, x3);
            }
            floatx4 acc2 = {0.f, 0.f, 0.f, 0.f};
            #pragma unroll
            for (int kt = 0; kt < 4; ++kt) {
                int lo0 = __builtin_amdgcn_ds_bpermute(addrA, (int)pk[2 * kt][0]);
                int hi0 = __builtin_amdgcn_ds_bpermute(addrA, (int)pk[2 * kt + 1][0]);
                int lo1 = __builtin_amdgcn_ds_bpermute(addrA, (int)pk[2 * kt][1]);
                int hi1 = __builtin_amdgcn_ds_bpermute(addrA, (int)pk[2 * kt + 1][1]);
                int lo2 = __builtin_amdgcn_ds_bpermute(addrB, (int)pk[2 * kt][0]);
                int hi2 = __builtin_amdgcn_ds_bpermute(addrB, (int)pk[2 * kt + 1][0]);
                int lo3 = __builtin_amdgcn_ds_bpermute(addrB, (int)pk[2 * kt][1]);
                int hi3 = __builtin_amdgcn_ds_bpermute(addrB, (int)pk[2 * kt + 1][1]);
                union { unsigned int u[4]; short8 s; } a2u;
                a2u.u[0] = (unsigned int)(hiSel ? hi0 : lo0);
                a2u.u[1] = (unsigned int)(hiSel ? hi1 : lo1);
                a2u.u[2] = (unsigned int)(hiSel ? hi2 : lo2);
                a2u.u[3] = (unsigned int)(hiSel ? hi3 : lo3);
                acc2 = __builtin_amdgcn_mfma_f32_16x16x32_bf16(a2u.s, pkW2[kt * 64 + lane], acc2, 0, 0, 0);
            }
            #pragma unroll
            for (int rr = 0; rr < 4; ++rr) {
                int lrow = tile * 16 + q * 4 + rr;     // 0..383
                int et = lrow / 3, i = lrow - et * 3;
                long ge = blockbase + et;
                float base = states[ge * 48 + i * 16 + m];
                out[ge * OUTD + i * 16 + m] = acc2[rr] + base + b2v;
            }
        }
    }
}

extern "C" void kernel_launch(void* const* d_in, const int* in_sizes, int n_in,
                              void* d_out, int out_size, void* d_ws, size_t ws_size,
                              hipStream_t stream) {
    const float* states = (const float*)d_in[0];
    const float* action = (const float*)d_in[1];
    const int* block_id = (const int*)d_in[2];
    const float* Wq = (const float*)d_in[3];
    const float* bq = (const float*)d_in[4];
    const float* Wk = (const float*)d_in[5];
    const float* bk = (const float*)d_in[6];
    const float* Wv = (const float*)d_in[7];
    const float* bv = (const float*)d_in[8];
    const float* W1 = (const float*)d_in[9];
    const float* b1 = (const float*)d_in[10];
    const float* W2 = (const float*)d_in[11];
    const float* b2 = (const float*)d_in[12];
    const float* Wc1 = (const float*)d_in[13];
    const float* bc1 = (const float*)d_in[14];
    const float* Wc2 = (const float*)d_in[15];
    const float* bc2 = (const float*)d_in[16];
    float* out = (float*)d_out;
    float* ws = (float*)d_ws;

    hipLaunchKernelGGL(prep_dots, dim3((NDOT + 3) / 4), dim3(256), 0, stream,
                       Wq, bq, Wk, bk, Wv, bv, W1, b1, ws);
    hipLaunchKernelGGL(prep_copy, dim3((NCOPY + 255) / 256), dim3(256), 0, stream,
                       W2, b2, Wc1, bc1, Wc2, bc2, ws);
    hipLaunchKernelGGL(main_kernel, dim3(BTOT / 128), dim3(256), 0, stream,
                       states, action, block_id, ws, out);
}